// Round 8
// baseline (261.108 us; speedup 1.0000x reference)
//
#include <hip/hip_runtime.h>
#include <hip/hip_bf16.h>
#include <cmath>

#define N_NODESC 20000
#define E_RAW    320000
#define E_TOTC   340000   // + self loops
#define HEADSC   4
#define FC       256      // HEADS*HID
#define NEG_SLOPE 0.2f

__device__ __forceinline__ int dstOf(const int* ei, int e) {
  return (e < E_RAW) ? ei[E_RAW + e] : (e - E_RAW);
}
__device__ __forceinline__ int srcOf(const int* ei, int e) {
  return (e < E_RAW) ? ei[e] : (e - E_RAW);
}
__device__ __forceinline__ float lrelu(float v) { return v > 0.f ? v : NEG_SLOPE * v; }

__device__ __forceinline__ unsigned short f2bf(float f) {
  __hip_bfloat16 h = __float2bfloat16(f);           // RN
  return reinterpret_cast<unsigned short&>(h);
}
__device__ __forceinline__ float bf2f(unsigned short u) {
  return __uint_as_float(((unsigned int)u) << 16);
}

// ---- GEMM + fused alpha: hfeat_bf16[N,256] = A[N,K] @ W[K,256]
// 16 rows/block, thread = 4 rows x 4 consecutive cols.
// W double-buffered in REGISTERS: next chunk's loads issue before current FMAs.
template<int K>
__global__ void gemm_kernel(const float* __restrict__ A, const float* __restrict__ W,
                            const float* __restrict__ a_src, const float* __restrict__ a_dst,
                            unsigned short* __restrict__ hb, float* __restrict__ as,
                            float* __restrict__ ad) {
  __shared__ float xs[16][K];
  const int t  = threadIdx.x;
  const int m  = t & 63;        // col group: cols 4m..4m+3
  const int rg = t >> 6;        // rows rg*4 .. rg*4+3
  const int n0 = blockIdx.x * 16;   // 20000/16 = 1250 exact
  for (int idx = t; idx < 16 * (K / 4); idx += 256) {
    int r = idx / (K / 4), c4 = idx - r * (K / 4);
    ((float4*)&xs[r][0])[c4] = ((const float4*)(A + (long)(n0 + r) * K))[c4];
  }
  const float* wbase = W + 4 * m;
  float4 wc0 = *(const float4*)(wbase + 0 * FC);
  float4 wc1 = *(const float4*)(wbase + 1 * FC);
  float4 wc2 = *(const float4*)(wbase + 2 * FC);
  float4 wc3 = *(const float4*)(wbase + 3 * FC);
  __syncthreads();
  float4 acc[4];
#pragma unroll
  for (int i = 0; i < 4; ++i) acc[i] = float4{0.f, 0.f, 0.f, 0.f};
  for (int k0 = 0; k0 < K; k0 += 4) {
    float4 wn0, wn1, wn2, wn3;
    if (k0 + 4 < K) {
      wn0 = *(const float4*)(wbase + (long)(k0 + 4) * FC);
      wn1 = *(const float4*)(wbase + (long)(k0 + 5) * FC);
      wn2 = *(const float4*)(wbase + (long)(k0 + 6) * FC);
      wn3 = *(const float4*)(wbase + (long)(k0 + 7) * FC);
    }
#pragma unroll
    for (int i = 0; i < 4; ++i) {
      float4 a = *(const float4*)&xs[rg * 4 + i][k0];
      acc[i].x = fmaf(a.x, wc0.x, acc[i].x); acc[i].y = fmaf(a.x, wc0.y, acc[i].y);
      acc[i].z = fmaf(a.x, wc0.z, acc[i].z); acc[i].w = fmaf(a.x, wc0.w, acc[i].w);
      acc[i].x = fmaf(a.y, wc1.x, acc[i].x); acc[i].y = fmaf(a.y, wc1.y, acc[i].y);
      acc[i].z = fmaf(a.y, wc1.z, acc[i].z); acc[i].w = fmaf(a.y, wc1.w, acc[i].w);
      acc[i].x = fmaf(a.z, wc2.x, acc[i].x); acc[i].y = fmaf(a.z, wc2.y, acc[i].y);
      acc[i].z = fmaf(a.z, wc2.z, acc[i].z); acc[i].w = fmaf(a.z, wc2.w, acc[i].w);
      acc[i].x = fmaf(a.w, wc3.x, acc[i].x); acc[i].y = fmaf(a.w, wc3.y, acc[i].y);
      acc[i].z = fmaf(a.w, wc3.z, acc[i].z); acc[i].w = fmaf(a.w, wc3.w, acc[i].w);
    }
    if (k0 + 4 < K) { wc0 = wn0; wc1 = wn1; wc2 = wn2; wc3 = wn3; }
  }
  const int cc = 4 * m;
  const int h  = m >> 4;        // head of this 4-col group
  float4 asv = *(const float4*)(a_src + cc);
  float4 adv = *(const float4*)(a_dst + cc);
#pragma unroll
  for (int i = 0; i < 4; ++i) {
    int n = n0 + rg * 4 + i;
    ushort4 pk;
    pk.x = f2bf(acc[i].x); pk.y = f2bf(acc[i].y);
    pk.z = f2bf(acc[i].z); pk.w = f2bf(acc[i].w);
    *(ushort4*)(hb + (long)n * FC + cc) = pk;
    float ps = acc[i].x * asv.x + acc[i].y * asv.y + acc[i].z * asv.z + acc[i].w * asv.w;
    float pd = acc[i].x * adv.x + acc[i].y * adv.y + acc[i].z * adv.z + acc[i].w * adv.w;
    for (int off = 8; off; off >>= 1) {
      ps += __shfl_down(ps, off, 16);
      pd += __shfl_down(pd, off, 16);
    }
    if ((m & 15) == 0) {
      as[n * HEADSC + h] = ps;
      ad[n * HEADSC + h] = pd;
    }
  }
}

// ------------- layer3 projection: h3[n] = act[n,:] . W3, + alphas ----------
__global__ void gemm3_kernel(const float* __restrict__ A, const float* __restrict__ W3,
                             const float* __restrict__ asc, const float* __restrict__ adc,
                             float* __restrict__ h3, float* __restrict__ as,
                             float* __restrict__ ad) {
  const int n = blockIdx.x;
  const int t = threadIdx.x;            // 256
  float v = A[(long)n * FC + t] * W3[t];
  for (int off = 32; off; off >>= 1) v += __shfl_down(v, off, 64);
  __shared__ float red[4];
  if ((t & 63) == 0) red[t >> 6] = v;
  __syncthreads();
  if (t == 0) {
    float s = red[0] + red[1] + red[2] + red[3];
    h3[n] = s;
    as[n] = s * asc[0];
    ad[n] = s * adc[0];
  }
}

// ----------------------------- CSR build -----------------------------------
__global__ void zero_deg(int* __restrict__ deg) {
  int i = blockIdx.x * 256 + threadIdx.x;
  if (i < N_NODESC) deg[i] = 0;
}

__global__ void deg_count(const int* __restrict__ ei, int* __restrict__ deg) {
  int e = blockIdx.x * 256 + threadIdx.x;
  if (e >= E_TOTC) return;
  atomicAdd(&deg[dstOf(ei, e)], 1);
}

__global__ void scan_kernel(const int* __restrict__ deg, int* __restrict__ row_ptr,
                            int* __restrict__ cursor) {
  __shared__ int partial[1024];
  const int t = threadIdx.x;                       // 1024 threads, single block
  const int PER = (N_NODESC + 1023) / 1024;        // 20
  const int base = t * PER;
  int s = 0;
  for (int i = 0; i < PER; ++i) {
    int idx = base + i;
    if (idx < N_NODESC) s += deg[idx];
  }
  partial[t] = s;
  __syncthreads();
  for (int off = 1; off < 1024; off <<= 1) {
    int v = (t >= off) ? partial[t - off] : 0;
    __syncthreads();
    partial[t] += v;
    __syncthreads();
  }
  int run = (t == 0) ? 0 : partial[t - 1];
  for (int i = 0; i < PER; ++i) {
    int idx = base + i;
    if (idx < N_NODESC) {
      row_ptr[idx] = run;
      cursor[idx]  = run;
      run += deg[idx];
    }
  }
  if (t == 1023) row_ptr[N_NODESC] = run;          // = E_TOTC
}

__global__ void fill_kernel(const int* __restrict__ ei, int* __restrict__ cursor,
                            int* __restrict__ col_src) {
  int e = blockIdx.x * 256 + threadIdx.x;
  if (e >= E_TOTC) return;
  int d = dstOf(ei, e);
  int pos = atomicAdd(&cursor[d], 1);
  col_src[pos] = srcOf(ei, e);
}

// --- softmax, H=4: one WAVE per node; lanes stride edges; xor-shuffle reduce
__global__ void softmax4_kernel(const int* __restrict__ row_ptr, const int* __restrict__ col_src,
                                const float4* __restrict__ as4, const float4* __restrict__ ad4,
                                float4* __restrict__ ebuf4, float4* __restrict__ denom4) {
  const int w = threadIdx.x >> 6, l = threadIdx.x & 63;
  const int n = blockIdx.x * 4 + w;
  if (n >= N_NODESC) return;
  const int j0 = row_ptr[n], j1 = row_ptr[n + 1];
  const float4 adv = ad4[n];
  float4 mx = float4{-INFINITY, -INFINITY, -INFINITY, -INFINITY};
  for (int j = j0 + l; j < j1; j += 64) {
    float4 a = as4[col_src[j]];
    float4 v;
    v.x = lrelu(a.x + adv.x); v.y = lrelu(a.y + adv.y);
    v.z = lrelu(a.z + adv.z); v.w = lrelu(a.w + adv.w);
    ebuf4[j] = v;
    mx.x = fmaxf(mx.x, v.x); mx.y = fmaxf(mx.y, v.y);
    mx.z = fmaxf(mx.z, v.z); mx.w = fmaxf(mx.w, v.w);
  }
  for (int off = 32; off; off >>= 1) {
    mx.x = fmaxf(mx.x, __shfl_xor(mx.x, off, 64));
    mx.y = fmaxf(mx.y, __shfl_xor(mx.y, off, 64));
    mx.z = fmaxf(mx.z, __shfl_xor(mx.z, off, 64));
    mx.w = fmaxf(mx.w, __shfl_xor(mx.w, off, 64));
  }
  float4 sm = float4{0.f, 0.f, 0.f, 0.f};
  for (int j = j0 + l; j < j1; j += 64) {
    float4 v = ebuf4[j];
    float4 e;
    e.x = expf(v.x - mx.x); e.y = expf(v.y - mx.y);
    e.z = expf(v.z - mx.z); e.w = expf(v.w - mx.w);
    ebuf4[j] = e;
    sm.x += e.x; sm.y += e.y; sm.z += e.z; sm.w += e.w;
  }
  for (int off = 32; off; off >>= 1) {
    sm.x += __shfl_xor(sm.x, off, 64);
    sm.y += __shfl_xor(sm.y, off, 64);
    sm.z += __shfl_xor(sm.z, off, 64);
    sm.w += __shfl_xor(sm.w, off, 64);
  }
  if (l == 0)
    denom4[n] = float4{1.f / sm.x, 1.f / sm.y, 1.f / sm.z, 1.f / sm.w};
}

// --- softmax, H=1: one wave per node ---
__global__ void softmax1_kernel(const int* __restrict__ row_ptr, const int* __restrict__ col_src,
                                const float* __restrict__ as, const float* __restrict__ ad,
                                float* __restrict__ ebuf, float* __restrict__ denom) {
  const int w = threadIdx.x >> 6, l = threadIdx.x & 63;
  const int n = blockIdx.x * 4 + w;
  if (n >= N_NODESC) return;
  const int j0 = row_ptr[n], j1 = row_ptr[n + 1];
  const float adv = ad[n];
  float mx = -INFINITY;
  for (int j = j0 + l; j < j1; j += 64) {
    float v = lrelu(as[col_src[j]] + adv);
    ebuf[j] = v;
    mx = fmaxf(mx, v);
  }
  for (int off = 32; off; off >>= 1) mx = fmaxf(mx, __shfl_xor(mx, off, 64));
  float sm = 0.f;
  for (int j = j0 + l; j < j1; j += 64) {
    float e = expf(ebuf[j] - mx);
    ebuf[j] = e;
    sm += e;
  }
  for (int off = 32; off; off >>= 1) sm += __shfl_xor(sm, off, 64);
  if (l == 0) denom[n] = 1.f / sm;
}

// --- aggregation: 1 node/block, 128 threads, thread = 2 channels (bf16x2) ---
template<bool ELU>
__global__ void agg_kernel(const int* __restrict__ row_ptr, const int* __restrict__ col_src,
                           const float* __restrict__ ebuf, const float* __restrict__ denom,
                           const unsigned short* __restrict__ hb, const float* __restrict__ b,
                           float* __restrict__ outbuf) {
  const int d = blockIdx.x;
  const int t = threadIdx.x;                       // 0..127, channel pair 2t,2t+1
  const int h = t >> 5;
  const int j0 = row_ptr[d], j1 = row_ptr[d + 1];
  const ushort2* hb2 = (const ushort2*)hb;         // 128 pairs per row
  float a0 = 0.f, a1 = 0.f;
  int j = j0;
  for (; j + 8 <= j1; j += 8) {
    int     s[8];
    ushort2 v[8];
    float   w[8];
#pragma unroll
    for (int u = 0; u < 8; ++u) s[u] = col_src[j + u];
#pragma unroll
    for (int u = 0; u < 8; ++u) v[u] = hb2[(long)s[u] * 128 + t];
#pragma unroll
    for (int u = 0; u < 8; ++u) w[u] = ebuf[(j + u) * HEADSC + h];
#pragma unroll
    for (int u = 0; u < 8; ++u) {
      a0 = fmaf(w[u], bf2f(v[u].x), a0);
      a1 = fmaf(w[u], bf2f(v[u].y), a1);
    }
  }
  for (; j < j1; ++j) {
    ushort2 v = hb2[(long)col_src[j] * 128 + t];
    float w = ebuf[j * HEADSC + h];
    a0 = fmaf(w, bf2f(v.x), a0);
    a1 = fmaf(w, bf2f(v.y), a1);
  }
  float dn = denom[d * HEADSC + h];
  float o0 = a0 * dn + b[2 * t];
  float o1 = a1 * dn + b[2 * t + 1];
  if (ELU) {
    o0 = o0 > 0.f ? o0 : expm1f(o0);
    o1 = o1 > 0.f ? o1 : expm1f(o1);
  }
  *(float2*)(outbuf + (long)d * FC + 2 * t) = float2{o0, o1};
}

// ------------- layer3 aggregation: wave per node, scalar -------------------
__global__ void agg3_kernel(const int* __restrict__ row_ptr, const int* __restrict__ col_src,
                            const float* __restrict__ ebuf, const float* __restrict__ denom,
                            const float* __restrict__ h3, const float* __restrict__ b3,
                            float* __restrict__ out) {
  const int wv = threadIdx.x >> 6;                 // 4 waves/block
  const int l  = threadIdx.x & 63;
  const int d  = blockIdx.x * 4 + wv;
  if (d >= N_NODESC) return;
  const int j0 = row_ptr[d], j1 = row_ptr[d + 1];
  float acc = 0.f;
  for (int j = j0 + l; j < j1; j += 64)
    acc = fmaf(ebuf[j], h3[col_src[j]], acc);
  for (int off = 32; off; off >>= 1) acc += __shfl_down(acc, off, 64);
  if (l == 0) out[d] = acc * denom[d] + b3[0];
}

extern "C" void kernel_launch(void* const* d_in, const int* in_sizes, int n_in,
                              void* d_out, int out_size, void* d_ws, size_t ws_size,
                              hipStream_t stream) {
  const float* x    = (const float*)d_in[0];
  const int*   ei   = (const int*)d_in[1];
  const float* W1   = (const float*)d_in[2];
  const float* as1  = (const float*)d_in[3];
  const float* ad1  = (const float*)d_in[4];
  const float* b1   = (const float*)d_in[5];
  const float* W2   = (const float*)d_in[6];
  const float* as2  = (const float*)d_in[7];
  const float* ad2  = (const float*)d_in[8];
  const float* b2   = (const float*)d_in[9];
  const float* W3   = (const float*)d_in[10];
  const float* as3  = (const float*)d_in[11];
  const float* ad3  = (const float*)d_in[12];
  const float* b3   = (const float*)d_in[13];
  float* out = (float*)d_out;

  float* ws    = (float*)d_ws;
  float*         act = ws;                                  // N*256 f32
  unsigned short* hb = (unsigned short*)(act + (size_t)N_NODESC * FC); // N*256 bf16
  float* wAs   = act + (size_t)N_NODESC * FC + (size_t)N_NODESC * FC / 2;
  float* wAd   = wAs   + (size_t)N_NODESC * HEADSC;
  float* denom = wAd   + (size_t)N_NODESC * HEADSC;
  float* ebuf  = denom + (size_t)N_NODESC * HEADSC;         // E_TOT*4
  float* h3    = ebuf  + (size_t)E_TOTC * HEADSC;           // N
  int*   ibase = (int*)(h3 + N_NODESC);
  int*   deg     = ibase;                 // N
  int*   row_ptr = deg + N_NODESC;        // N+1
  int*   cursor  = row_ptr + N_NODESC + 1;// N
  int*   col_src = cursor + N_NODESC;     // E_TOT

  const int gridE  = (E_TOTC + 255) / 256;
  const int gridN  = (N_NODESC + 255) / 256;
  const int gridN4 = (N_NODESC + 3) / 4;
  const int gemmG  = N_NODESC / 16;       // 1250, exact

  // ---------------- CSR build (edge_index shared by all layers) ------------
  zero_deg<<<gridN, 256, 0, stream>>>(deg);
  deg_count<<<gridE, 256, 0, stream>>>(ei, deg);
  scan_kernel<<<1, 1024, 0, stream>>>(deg, row_ptr, cursor);
  fill_kernel<<<gridE, 256, 0, stream>>>(ei, cursor, col_src);

  // ---------------- layer 1 ----------------
  gemm_kernel<128><<<gemmG, 256, 0, stream>>>(x, W1, as1, ad1, hb, wAs, wAd);
  softmax4_kernel<<<gridN4, 256, 0, stream>>>(row_ptr, col_src, (const float4*)wAs,
                                              (const float4*)wAd, (float4*)ebuf, (float4*)denom);
  agg_kernel<true><<<N_NODESC, 128, 0, stream>>>(row_ptr, col_src, ebuf, denom, hb, b1, act);

  // ---------------- layer 2 ----------------
  gemm_kernel<256><<<gemmG, 256, 0, stream>>>(act, W2, as2, ad2, hb, wAs, wAd);
  softmax4_kernel<<<gridN4, 256, 0, stream>>>(row_ptr, col_src, (const float4*)wAs,
                                              (const float4*)wAd, (float4*)ebuf, (float4*)denom);
  agg_kernel<true><<<N_NODESC, 128, 0, stream>>>(row_ptr, col_src, ebuf, denom, hb, b2, act);

  // ---------------- layer 3 (heads=1, out=1) ----------------
  gemm3_kernel<<<N_NODESC, 256, 0, stream>>>(act, W3, as3, ad3, h3, wAs, wAd);
  softmax1_kernel<<<gridN4, 256, 0, stream>>>(row_ptr, col_src, wAs, wAd, ebuf, denom);
  agg3_kernel<<<gridN4, 256, 0, stream>>>(row_ptr, col_src, ebuf, denom, h3, b3, out);
}

// Round 9
// 250.564 us; speedup vs baseline: 1.0421x; 1.0421x over previous
//
#include <hip/hip_runtime.h>
#include <hip/hip_bf16.h>
#include <cmath>

#define N_NODESC 20000
#define E_RAW    320000
#define E_TOTC   340000   // + self loops
#define HEADSC   4
#define FC       256      // HEADS*HID
#define NEG_SLOPE 0.2f

__device__ __forceinline__ int dstOf(const int* ei, int e) {
  return (e < E_RAW) ? ei[E_RAW + e] : (e - E_RAW);
}
__device__ __forceinline__ int srcOf(const int* ei, int e) {
  return (e < E_RAW) ? ei[e] : (e - E_RAW);
}
__device__ __forceinline__ float lrelu(float v) { return v > 0.f ? v : NEG_SLOPE * v; }

__device__ __forceinline__ unsigned short f2bf(float f) {
  __hip_bfloat16 h = __float2bfloat16(f);           // RN
  return reinterpret_cast<unsigned short&>(h);
}
__device__ __forceinline__ float bf2f(unsigned short u) {
  return __uint_as_float(((unsigned int)u) << 16);
}

// ---- GEMM + fused alpha: hfeat_bf16[N,256] = A[N,K] @ W[K,256]
// 16 rows/block, K SPLIT ACROSS WAVES: wave w handles k in [w*K/4,(w+1)*K/4)
// for ALL 16 rows (acc = float4[16]); W is read once per block (L2-traffic /4).
// Cross-wave combine via LDS red[16][256], then bf16 store + fused alpha.
template<int K>
__global__ void gemm_kernel(const float* __restrict__ A, const float* __restrict__ W,
                            const float* __restrict__ a_src, const float* __restrict__ a_dst,
                            unsigned short* __restrict__ hb, float* __restrict__ as,
                            float* __restrict__ ad) {
  __shared__ float xs[16][K];
  __shared__ float red[16][FC];
  const int t  = threadIdx.x;
  const int m  = t & 63;            // col group: cols 4m..4m+3
  const int w  = t >> 6;            // wave id 0..3
  const int n0 = blockIdx.x * 16;   // 20000/16 = 1250 exact

  for (int idx = t; idx < 16 * (K / 4); idx += 256) {
    int r = idx / (K / 4), c4 = idx - r * (K / 4);
    ((float4*)&xs[r][0])[c4] = ((const float4*)(A + (long)(n0 + r) * K))[c4];
  }
  __syncthreads();

  float4 acc[16];
#pragma unroll
  for (int r = 0; r < 16; ++r) acc[r] = float4{0.f, 0.f, 0.f, 0.f};

  const float* wbase = W + 4 * m;
  const int kbeg = w * (K / 4), kend = kbeg + (K / 4);
  for (int k0 = kbeg; k0 < kend; k0 += 4) {
    float4 w0 = *(const float4*)(wbase + (long)(k0 + 0) * FC);
    float4 w1 = *(const float4*)(wbase + (long)(k0 + 1) * FC);
    float4 w2 = *(const float4*)(wbase + (long)(k0 + 2) * FC);
    float4 w3 = *(const float4*)(wbase + (long)(k0 + 3) * FC);
#pragma unroll
    for (int r = 0; r < 16; ++r) {
      float4 a = ((const float4*)&xs[r][0])[k0 >> 2];
      acc[r].x = fmaf(a.x, w0.x, acc[r].x); acc[r].y = fmaf(a.x, w0.y, acc[r].y);
      acc[r].z = fmaf(a.x, w0.z, acc[r].z); acc[r].w = fmaf(a.x, w0.w, acc[r].w);
      acc[r].x = fmaf(a.y, w1.x, acc[r].x); acc[r].y = fmaf(a.y, w1.y, acc[r].y);
      acc[r].z = fmaf(a.y, w1.z, acc[r].z); acc[r].w = fmaf(a.y, w1.w, acc[r].w);
      acc[r].x = fmaf(a.z, w2.x, acc[r].x); acc[r].y = fmaf(a.z, w2.y, acc[r].y);
      acc[r].z = fmaf(a.z, w2.z, acc[r].z); acc[r].w = fmaf(a.z, w2.w, acc[r].w);
      acc[r].x = fmaf(a.w, w3.x, acc[r].x); acc[r].y = fmaf(a.w, w3.y, acc[r].y);
      acc[r].z = fmaf(a.w, w3.z, acc[r].z); acc[r].w = fmaf(a.w, w3.w, acc[r].w);
    }
  }

  // cross-wave reduction: wave 0 writes, waves 1..3 add (barriers are block-wide)
  float4* red4row;
  if (w == 0) {
#pragma unroll
    for (int r = 0; r < 16; ++r) ((float4*)&red[r][0])[m] = acc[r];
  }
  __syncthreads();
  if (w == 1) {
#pragma unroll
    for (int r = 0; r < 16; ++r) {
      float4 v = ((float4*)&red[r][0])[m];
      v.x += acc[r].x; v.y += acc[r].y; v.z += acc[r].z; v.w += acc[r].w;
      ((float4*)&red[r][0])[m] = v;
    }
  }
  __syncthreads();
  if (w == 2) {
#pragma unroll
    for (int r = 0; r < 16; ++r) {
      float4 v = ((float4*)&red[r][0])[m];
      v.x += acc[r].x; v.y += acc[r].y; v.z += acc[r].z; v.w += acc[r].w;
      ((float4*)&red[r][0])[m] = v;
    }
  }
  __syncthreads();
  if (w == 3) {
#pragma unroll
    for (int r = 0; r < 16; ++r) {
      float4 v = ((float4*)&red[r][0])[m];
      v.x += acc[r].x; v.y += acc[r].y; v.z += acc[r].z; v.w += acc[r].w;
      ((float4*)&red[r][0])[m] = v;
    }
  }
  __syncthreads();

  // epilogue: wave w handles rows 4w..4w+3
  const int cc = 4 * m;
  const int h  = m >> 4;
  float4 asv = *(const float4*)(a_src + cc);
  float4 adv = *(const float4*)(a_dst + cc);
#pragma unroll
  for (int i = 0; i < 4; ++i) {
    int r = w * 4 + i;
    int n = n0 + r;
    float4 v = ((float4*)&red[r][0])[m];
    ushort4 pk;
    pk.x = f2bf(v.x); pk.y = f2bf(v.y);
    pk.z = f2bf(v.z); pk.w = f2bf(v.w);
    *(ushort4*)(hb + (long)n * FC + cc) = pk;
    float ps = v.x * asv.x + v.y * asv.y + v.z * asv.z + v.w * asv.w;
    float pd = v.x * adv.x + v.y * adv.y + v.z * adv.z + v.w * adv.w;
    for (int off = 8; off; off >>= 1) {
      ps += __shfl_down(ps, off, 16);
      pd += __shfl_down(pd, off, 16);
    }
    if ((m & 15) == 0) {
      as[n * HEADSC + h] = ps;
      ad[n * HEADSC + h] = pd;
    }
  }
}

// ------------- layer3 projection: h3[n] = act[n,:] . W3, + alphas ----------
__global__ void gemm3_kernel(const float* __restrict__ A, const float* __restrict__ W3,
                             const float* __restrict__ asc, const float* __restrict__ adc,
                             float* __restrict__ h3, float* __restrict__ as,
                             float* __restrict__ ad) {
  const int n = blockIdx.x;
  const int t = threadIdx.x;            // 256
  float v = A[(long)n * FC + t] * W3[t];
  for (int off = 32; off; off >>= 1) v += __shfl_down(v, off, 64);
  __shared__ float red[4];
  if ((t & 63) == 0) red[t >> 6] = v;
  __syncthreads();
  if (t == 0) {
    float s = red[0] + red[1] + red[2] + red[3];
    h3[n] = s;
    as[n] = s * asc[0];
    ad[n] = s * adc[0];
  }
}

// ----------------------------- CSR build -----------------------------------
__global__ void zero_deg(int* __restrict__ deg) {
  int i = blockIdx.x * 256 + threadIdx.x;
  if (i < N_NODESC) deg[i] = 0;
}

__global__ void deg_count(const int* __restrict__ ei, int* __restrict__ deg) {
  int e = blockIdx.x * 256 + threadIdx.x;
  if (e >= E_TOTC) return;
  atomicAdd(&deg[dstOf(ei, e)], 1);
}

__global__ void scan_kernel(const int* __restrict__ deg, int* __restrict__ row_ptr,
                            int* __restrict__ cursor) {
  __shared__ int partial[1024];
  const int t = threadIdx.x;                       // 1024 threads, single block
  const int PER = (N_NODESC + 1023) / 1024;        // 20
  const int base = t * PER;
  int s = 0;
  for (int i = 0; i < PER; ++i) {
    int idx = base + i;
    if (idx < N_NODESC) s += deg[idx];
  }
  partial[t] = s;
  __syncthreads();
  for (int off = 1; off < 1024; off <<= 1) {
    int v = (t >= off) ? partial[t - off] : 0;
    __syncthreads();
    partial[t] += v;
    __syncthreads();
  }
  int run = (t == 0) ? 0 : partial[t - 1];
  for (int i = 0; i < PER; ++i) {
    int idx = base + i;
    if (idx < N_NODESC) {
      row_ptr[idx] = run;
      cursor[idx]  = run;
      run += deg[idx];
    }
  }
  if (t == 1023) row_ptr[N_NODESC] = run;          // = E_TOTC
}

__global__ void fill_kernel(const int* __restrict__ ei, int* __restrict__ cursor,
                            int* __restrict__ col_src) {
  int e = blockIdx.x * 256 + threadIdx.x;
  if (e >= E_TOTC) return;
  int d = dstOf(ei, e);
  int pos = atomicAdd(&cursor[d], 1);
  col_src[pos] = srcOf(ei, e);
}

// --- softmax, H=4: one WAVE per node; lanes stride edges; xor-shuffle reduce
__global__ void softmax4_kernel(const int* __restrict__ row_ptr, const int* __restrict__ col_src,
                                const float4* __restrict__ as4, const float4* __restrict__ ad4,
                                float4* __restrict__ ebuf4, float4* __restrict__ denom4) {
  const int w = threadIdx.x >> 6, l = threadIdx.x & 63;
  const int n = blockIdx.x * 4 + w;
  if (n >= N_NODESC) return;
  const int j0 = row_ptr[n], j1 = row_ptr[n + 1];
  const float4 adv = ad4[n];
  float4 mx = float4{-INFINITY, -INFINITY, -INFINITY, -INFINITY};
  for (int j = j0 + l; j < j1; j += 64) {
    float4 a = as4[col_src[j]];
    float4 v;
    v.x = lrelu(a.x + adv.x); v.y = lrelu(a.y + adv.y);
    v.z = lrelu(a.z + adv.z); v.w = lrelu(a.w + adv.w);
    ebuf4[j] = v;
    mx.x = fmaxf(mx.x, v.x); mx.y = fmaxf(mx.y, v.y);
    mx.z = fmaxf(mx.z, v.z); mx.w = fmaxf(mx.w, v.w);
  }
  for (int off = 32; off; off >>= 1) {
    mx.x = fmaxf(mx.x, __shfl_xor(mx.x, off, 64));
    mx.y = fmaxf(mx.y, __shfl_xor(mx.y, off, 64));
    mx.z = fmaxf(mx.z, __shfl_xor(mx.z, off, 64));
    mx.w = fmaxf(mx.w, __shfl_xor(mx.w, off, 64));
  }
  float4 sm = float4{0.f, 0.f, 0.f, 0.f};
  for (int j = j0 + l; j < j1; j += 64) {
    float4 v = ebuf4[j];
    float4 e;
    e.x = expf(v.x - mx.x); e.y = expf(v.y - mx.y);
    e.z = expf(v.z - mx.z); e.w = expf(v.w - mx.w);
    ebuf4[j] = e;
    sm.x += e.x; sm.y += e.y; sm.z += e.z; sm.w += e.w;
  }
  for (int off = 32; off; off >>= 1) {
    sm.x += __shfl_xor(sm.x, off, 64);
    sm.y += __shfl_xor(sm.y, off, 64);
    sm.z += __shfl_xor(sm.z, off, 64);
    sm.w += __shfl_xor(sm.w, off, 64);
  }
  if (l == 0)
    denom4[n] = float4{1.f / sm.x, 1.f / sm.y, 1.f / sm.z, 1.f / sm.w};
}

// --- softmax, H=1: one wave per node ---
__global__ void softmax1_kernel(const int* __restrict__ row_ptr, const int* __restrict__ col_src,
                                const float* __restrict__ as, const float* __restrict__ ad,
                                float* __restrict__ ebuf, float* __restrict__ denom) {
  const int w = threadIdx.x >> 6, l = threadIdx.x & 63;
  const int n = blockIdx.x * 4 + w;
  if (n >= N_NODESC) return;
  const int j0 = row_ptr[n], j1 = row_ptr[n + 1];
  const float adv = ad[n];
  float mx = -INFINITY;
  for (int j = j0 + l; j < j1; j += 64) {
    float v = lrelu(as[col_src[j]] + adv);
    ebuf[j] = v;
    mx = fmaxf(mx, v);
  }
  for (int off = 32; off; off >>= 1) mx = fmaxf(mx, __shfl_xor(mx, off, 64));
  float sm = 0.f;
  for (int j = j0 + l; j < j1; j += 64) {
    float e = expf(ebuf[j] - mx);
    ebuf[j] = e;
    sm += e;
  }
  for (int off = 32; off; off >>= 1) sm += __shfl_xor(sm, off, 64);
  if (l == 0) denom[n] = 1.f / sm;
}

// --- aggregation: 1 node/block, 128 threads, thread = 2 channels (bf16x2) ---
template<bool ELU>
__global__ void agg_kernel(const int* __restrict__ row_ptr, const int* __restrict__ col_src,
                           const float* __restrict__ ebuf, const float* __restrict__ denom,
                           const unsigned short* __restrict__ hb, const float* __restrict__ b,
                           float* __restrict__ outbuf) {
  const int d = blockIdx.x;
  const int t = threadIdx.x;                       // 0..127, channel pair 2t,2t+1
  const int h = t >> 5;
  const int j0 = row_ptr[d], j1 = row_ptr[d + 1];
  const ushort2* hb2 = (const ushort2*)hb;         // 128 pairs per row
  float a0 = 0.f, a1 = 0.f;
  int j = j0;
  for (; j + 8 <= j1; j += 8) {
    int     s[8];
    ushort2 v[8];
    float   w[8];
#pragma unroll
    for (int u = 0; u < 8; ++u) s[u] = col_src[j + u];
#pragma unroll
    for (int u = 0; u < 8; ++u) v[u] = hb2[(long)s[u] * 128 + t];
#pragma unroll
    for (int u = 0; u < 8; ++u) w[u] = ebuf[(j + u) * HEADSC + h];
#pragma unroll
    for (int u = 0; u < 8; ++u) {
      a0 = fmaf(w[u], bf2f(v[u].x), a0);
      a1 = fmaf(w[u], bf2f(v[u].y), a1);
    }
  }
  for (; j < j1; ++j) {
    ushort2 v = hb2[(long)col_src[j] * 128 + t];
    float w = ebuf[j * HEADSC + h];
    a0 = fmaf(w, bf2f(v.x), a0);
    a1 = fmaf(w, bf2f(v.y), a1);
  }
  float dn = denom[d * HEADSC + h];
  float o0 = a0 * dn + b[2 * t];
  float o1 = a1 * dn + b[2 * t + 1];
  if (ELU) {
    o0 = o0 > 0.f ? o0 : expm1f(o0);
    o1 = o1 > 0.f ? o1 : expm1f(o1);
  }
  *(float2*)(outbuf + (long)d * FC + 2 * t) = float2{o0, o1};
}

// ------------- layer3 aggregation: wave per node, scalar -------------------
__global__ void agg3_kernel(const int* __restrict__ row_ptr, const int* __restrict__ col_src,
                            const float* __restrict__ ebuf, const float* __restrict__ denom,
                            const float* __restrict__ h3, const float* __restrict__ b3,
                            float* __restrict__ out) {
  const int wv = threadIdx.x >> 6;                 // 4 waves/block
  const int l  = threadIdx.x & 63;
  const int d  = blockIdx.x * 4 + wv;
  if (d >= N_NODESC) return;
  const int j0 = row_ptr[d], j1 = row_ptr[d + 1];
  float acc = 0.f;
  for (int j = j0 + l; j < j1; j += 64)
    acc = fmaf(ebuf[j], h3[col_src[j]], acc);
  for (int off = 32; off; off >>= 1) acc += __shfl_down(acc, off, 64);
  if (l == 0) out[d] = acc * denom[d] + b3[0];
}

extern "C" void kernel_launch(void* const* d_in, const int* in_sizes, int n_in,
                              void* d_out, int out_size, void* d_ws, size_t ws_size,
                              hipStream_t stream) {
  const float* x    = (const float*)d_in[0];
  const int*   ei   = (const int*)d_in[1];
  const float* W1   = (const float*)d_in[2];
  const float* as1  = (const float*)d_in[3];
  const float* ad1  = (const float*)d_in[4];
  const float* b1   = (const float*)d_in[5];
  const float* W2   = (const float*)d_in[6];
  const float* as2  = (const float*)d_in[7];
  const float* ad2  = (const float*)d_in[8];
  const float* b2   = (const float*)d_in[9];
  const float* W3   = (const float*)d_in[10];
  const float* as3  = (const float*)d_in[11];
  const float* ad3  = (const float*)d_in[12];
  const float* b3   = (const float*)d_in[13];
  float* out = (float*)d_out;

  float* ws    = (float*)d_ws;
  float*         act = ws;                                  // N*256 f32
  unsigned short* hb = (unsigned short*)(act + (size_t)N_NODESC * FC); // N*256 bf16
  float* wAs   = act + (size_t)N_NODESC * FC + (size_t)N_NODESC * FC / 2;
  float* wAd   = wAs   + (size_t)N_NODESC * HEADSC;
  float* denom = wAd   + (size_t)N_NODESC * HEADSC;
  float* ebuf  = denom + (size_t)N_NODESC * HEADSC;         // E_TOT*4
  float* h3    = ebuf  + (size_t)E_TOTC * HEADSC;           // N
  int*   ibase = (int*)(h3 + N_NODESC);
  int*   deg     = ibase;                 // N
  int*   row_ptr = deg + N_NODESC;        // N+1
  int*   cursor  = row_ptr + N_NODESC + 1;// N
  int*   col_src = cursor + N_NODESC;     // E_TOT

  const int gridE  = (E_TOTC + 255) / 256;
  const int gridN  = (N_NODESC + 255) / 256;
  const int gridN4 = (N_NODESC + 3) / 4;
  const int gemmG  = N_NODESC / 16;       // 1250, exact

  // ---------------- CSR build (edge_index shared by all layers) ------------
  zero_deg<<<gridN, 256, 0, stream>>>(deg);
  deg_count<<<gridE, 256, 0, stream>>>(ei, deg);
  scan_kernel<<<1, 1024, 0, stream>>>(deg, row_ptr, cursor);
  fill_kernel<<<gridE, 256, 0, stream>>>(ei, cursor, col_src);

  // ---------------- layer 1 ----------------
  gemm_kernel<128><<<gemmG, 256, 0, stream>>>(x, W1, as1, ad1, hb, wAs, wAd);
  softmax4_kernel<<<gridN4, 256, 0, stream>>>(row_ptr, col_src, (const float4*)wAs,
                                              (const float4*)wAd, (float4*)ebuf, (float4*)denom);
  agg_kernel<true><<<N_NODESC, 128, 0, stream>>>(row_ptr, col_src, ebuf, denom, hb, b1, act);

  // ---------------- layer 2 ----------------
  gemm_kernel<256><<<gemmG, 256, 0, stream>>>(act, W2, as2, ad2, hb, wAs, wAd);
  softmax4_kernel<<<gridN4, 256, 0, stream>>>(row_ptr, col_src, (const float4*)wAs,
                                              (const float4*)wAd, (float4*)ebuf, (float4*)denom);
  agg_kernel<true><<<N_NODESC, 128, 0, stream>>>(row_ptr, col_src, ebuf, denom, hb, b2, act);

  // ---------------- layer 3 (heads=1, out=1) ----------------
  gemm3_kernel<<<N_NODESC, 256, 0, stream>>>(act, W3, as3, ad3, h3, wAs, wAd);
  softmax1_kernel<<<gridN4, 256, 0, stream>>>(row_ptr, col_src, wAs, wAd, ebuf, denom);
  agg3_kernel<<<gridN4, 256, 0, stream>>>(row_ptr, col_src, ebuf, denom, h3, b3, out);
}